// Round 8
// baseline (149.705 us; speedup 1.0000x reference)
//
#include <hip/hip_runtime.h>
#include <stdint.h>

// ---------------- types ----------------
using f32x4  = __attribute__((ext_vector_type(4))) float;
using short8 = __attribute__((ext_vector_type(8))) short;
using u16x4  = __attribute__((ext_vector_type(4))) unsigned short;

#define MFMA(a, b, c) __builtin_amdgcn_mfma_f32_16x16x32_bf16((a), (b), (c), 0, 0, 0)
#define GLOBAL_AS __attribute__((address_space(1)))
#define LDS_AS    __attribute__((address_space(3)))

#define XDIM 256
#define FDIM 512
#define EPS  1e-6f

// ---- workspace layout (bytes) ----
#define QT_OFF    0u          // [512][256] bf16 = 262144
#define KT_OFF    262144u
#define VT_OFF    524288u
#define CTXT_OFF  786432u     // [32][64 e][64 d] bf16 = 262144
#define KVB_OFF   1048576u    // [32768][256] bf16 (pre-swizzled) = 16 MB
#define XB_OFF    17825792u   // [32768][256] bf16 (pre-swizzled) = 16 MB
#define PART_OFF  34603008u   // [2048][64 d][64 e] f32 = 32 MB
// total = 68157440 (65 MB)

// round-to-nearest-even f32 -> bf16 bits
static __device__ __forceinline__ unsigned short f2bf(float f) {
  unsigned u = __float_as_uint(f);
  unsigned r = u + 0x7FFFu + ((u >> 16) & 1u);
  return (unsigned short)(r >> 16);
}

static __device__ __forceinline__ void async_copy16(const void* g, void* l) {
  __builtin_amdgcn_global_load_lds((GLOBAL_AS const void*)g, (LDS_AS void*)l, 16, 0, 0);
}

// Stage 64 rows x 512 B of pre-swizzled bf16 (row stride 512 B) into linear LDS
// [64][512] via global_load_lds. Wave w covers rows [w*16, w*16+16).
static __device__ __forceinline__ void stage_a_async(const unsigned short* src_rows,
                                                     int w, int lane, char* Alds) {
#pragma unroll
  for (int i = 0; i < 8; ++i) {
    const int r = w * 16 + i * 2 + (lane >> 5);
    async_copy16(src_rows + (size_t)r * 256 + (lane & 31) * 8,
                 Alds + (w * 8 + i) * 1024);
  }
}

// Per-row LayerNorm over the wave's 64-col chunk, M_REP row-fragments.
template <int M_REP>
static __device__ __forceinline__ void chunk_layernorm(f32x4 acc[M_REP][4], const float* sc,
                                                       const float* bs, int lane) {
  const int lr = lane & 15;
  float scl[4], bia[4];
#pragma unroll
  for (int nt = 0; nt < 4; ++nt) { scl[nt] = sc[nt * 16 + lr]; bia[nt] = bs[nt * 16 + lr]; }
#pragma unroll
  for (int mt = 0; mt < M_REP; ++mt) {
#pragma unroll
    for (int j = 0; j < 4; ++j) {
      float a0 = acc[mt][0][j], a1 = acc[mt][1][j], a2 = acc[mt][2][j], a3 = acc[mt][3][j];
      float s  = a0 + a1 + a2 + a3;
      float s2 = a0 * a0 + a1 * a1 + a2 * a2 + a3 * a3;
#pragma unroll
      for (int off = 1; off < 16; off <<= 1) {
        s  += __shfl_xor(s, off, 16);
        s2 += __shfl_xor(s2, off, 16);
      }
      const float mu  = s * (1.0f / 64.0f);
      const float var = s2 * (1.0f / 64.0f) - mu * mu;
      const float rs  = rsqrtf(var + EPS);
#pragma unroll
      for (int nt = 0; nt < 4; ++nt)
        acc[mt][nt][j] = (acc[mt][nt][j] - mu) * rs * scl[nt] + bia[nt];
    }
  }
}

// ---------------- kernel 1: prep ----------------
// blocks [0,2048):   kv f32 -> kvb bf16, pre-swizzled (chunk c -> c ^ (row&7))
// blocks [2048,4096): x  f32 -> xb  bf16, pre-swizzled
// blocks [4096,5632): weight transpose/cast
__global__ void prep_kernel(const float* __restrict__ kv, const float* __restrict__ x,
                            const float* __restrict__ Q, const float* __restrict__ K,
                            const float* __restrict__ V, const float* __restrict__ ls,
                            unsigned short* __restrict__ kvb, unsigned short* __restrict__ xb,
                            unsigned short* __restrict__ Qt, unsigned short* __restrict__ Kt,
                            unsigned short* __restrict__ Vt) {
  const int bid = blockIdx.x, tid = threadIdx.x;
  if (bid < 4096) {
    const int sel = bid >> 11;                    // 0 = kv, 1 = x
    const float* src = sel ? x : kv;
    unsigned short* dst = sel ? xb : kvb;
    const size_t e16 = ((size_t)(bid & 2047) * 256 + tid) * 16;
    const int row = (int)(e16 >> 8);
    const int col = (int)(e16 & 255);
    const int c0 = col >> 3;                      // 16B chunk index (even)
    const int s = row & 7;
    const float* sp = src + e16;
    short8 v0, v1;
#pragma unroll
    for (int j = 0; j < 8; ++j) v0[j] = (short)f2bf(sp[j]);
#pragma unroll
    for (int j = 0; j < 8; ++j) v1[j] = (short)f2bf(sp[8 + j]);
    unsigned short* drow = dst + (size_t)row * 256;
    *(short8*)(drow + ((c0 ^ s) << 3))       = v0;
    *(short8*)(drow + (((c0 + 1) ^ s) << 3)) = v1;
  } else {
    const int flat = (bid - 4096) * 256 + tid;    // < 3*131072
    const int mat = flat >> 17;
    const int rem = flat & 131071;
    const int f = rem & 511;
    const int k = rem >> 9;
    if (mat == 0)      Qt[f * 256 + k] = f2bf(Q[k * 512 + f]);
    else if (mat == 1) Kt[f * 256 + k] = f2bf(K[k * 512 + f]);
    else               Vt[f * 256 + k] = f2bf(V[k * 512 + f] * expf(ls[f]));
  }
}

// ---------------- kernel 2: kv projections + LN + partial ctx ----------------
// grid 2048: rb = bid>>2 (64-row tile), nb = bid&3 (128-feature quarter).
// Wave w = (wr<<1)|wc: rows [wr*32, wr*32+32), feature chunk wc (64 cols).
// acc = 32 regs per matrix -> 3 waves/SIMD.
__launch_bounds__(256, 3)
__global__ void kv_ctx_kernel(const unsigned short* __restrict__ kvb,
                              const unsigned short* __restrict__ Kt,
                              const unsigned short* __restrict__ Vt,
                              const float* __restrict__ lnk_s, const float* __restrict__ lnk_b,
                              const float* __restrict__ lnv_s, const float* __restrict__ lnv_b,
                              float* __restrict__ partials) {
  __shared__ __align__(16) char smem[32768];   // phase1: A [64][512] swz; phase2: knT/vnT

  const int tid = threadIdx.x, lane = tid & 63, w = tid >> 6;
  const int wr = w >> 1, wc = w & 1;
  const int bid = blockIdx.x, rb = bid >> 2, nb = bid & 3;
  const int row0 = rb * 64;
  const int lr = lane & 15, lk = lane >> 4;

  stage_a_async(kvb + (size_t)row0 * 256, w, lane, smem);

  const f32x4 z4 = {0.f, 0.f, 0.f, 0.f};
  f32x4 acck[2][4], accv[2][4];
#pragma unroll
  for (int i = 0; i < 2; ++i)
#pragma unroll
    for (int j = 0; j < 4; ++j) { acck[i][j] = z4; accv[i][j] = z4; }

  const unsigned short* kb = Kt + (size_t)(nb * 128 + wc * 64) * 256;
  const unsigned short* vb = Vt + (size_t)(nb * 128 + wc * 64) * 256;

  __syncthreads();   // staging (vmcnt drain) complete

  // ---- barrier-free GEMM over k=256 (4 x BK=64) ----
#pragma unroll
  for (int ks = 0; ks < 4; ++ks) {
    short8 bk[8], bv[8];
#pragma unroll
    for (int nt = 0; nt < 4; ++nt) {
      const unsigned short* kr = kb + (size_t)(nt * 16 + lr) * 256 + ks * 64 + lk * 8;
      const unsigned short* vr = vb + (size_t)(nt * 16 + lr) * 256 + ks * 64 + lk * 8;
      bk[nt * 2] = *(const short8*)(kr); bk[nt * 2 + 1] = *(const short8*)(kr + 32);
      bv[nt * 2] = *(const short8*)(vr); bv[nt * 2 + 1] = *(const short8*)(vr + 32);
    }
    short8 a0[2], a1[2];
#pragma unroll
    for (int mt = 0; mt < 2; ++mt) {
      const int row = wr * 32 + mt * 16 + lr;
      const int sw = (row & 7) << 4;
      a0[mt] = *(const short8*)(smem + row * 512 + ((ks * 128 + lk * 16) ^ sw));
      a1[mt] = *(const short8*)(smem + row * 512 + ((ks * 128 + 64 + lk * 16) ^ sw));
    }
#pragma unroll
    for (int mt = 0; mt < 2; ++mt)
#pragma unroll
      for (int nt = 0; nt < 4; ++nt) {
        acck[mt][nt] = MFMA(a0[mt], bk[nt * 2],     acck[mt][nt]);
        acck[mt][nt] = MFMA(a1[mt], bk[nt * 2 + 1], acck[mt][nt]);
      }
#pragma unroll
    for (int mt = 0; mt < 2; ++mt)
#pragma unroll
      for (int nt = 0; nt < 4; ++nt) {
        accv[mt][nt] = MFMA(a0[mt], bv[nt * 2],     accv[mt][nt]);
        accv[mt][nt] = MFMA(a1[mt], bv[nt * 2 + 1], accv[mt][nt]);
      }
  }

  chunk_layernorm<2>(acck, lnk_s, lnk_b, lane);
  chunk_layernorm<2>(accv, lnv_s, lnv_b, lane);

  // ---- ctx phase: ctx[d][e] = sum over t=128 (2 chunks x 64 rows) ----
  char* knT = smem;            // [64 d][256 B] (128 t), xor-swizzled
  char* vnT = smem + 16384;

  __syncthreads();             // all A reads done; region reused
#pragma unroll
  for (int mt = 0; mt < 2; ++mt) {
    const int t = wc * 64 + wr * 32 + mt * 16 + lk * 4;   // j adds 0..3
#pragma unroll
    for (int nt = 0; nt < 4; ++nt) {
      const int d = nt * 16 + lr;
      u16x4 pk, pv;
#pragma unroll
      for (int j = 0; j < 4; ++j) { pk[j] = f2bf(acck[mt][nt][j]); pv[j] = f2bf(accv[mt][nt][j]); }
      const int boff = d * 256 + ((t * 2) ^ ((d & 7) << 4));
      *(u16x4*)(knT + boff) = pk;
      *(u16x4*)(vnT + boff) = pv;
    }
  }
  __syncthreads();

  f32x4 cacc[4];
#pragma unroll
  for (int i = 0; i < 4; ++i) cacc[i] = z4;
  const int drow = w * 16 + lr;
#pragma unroll
  for (int s = 0; s < 4; ++s) {
    const short8 a = *(const short8*)(knT + drow * 256 + ((s * 64 + lk * 16) ^ ((drow & 7) << 4)));
#pragma unroll
    for (int nt = 0; nt < 4; ++nt) {
      const int e = nt * 16 + lr;
      const short8 b = *(const short8*)(vnT + e * 256 + ((s * 64 + lk * 16) ^ ((e & 7) << 4)));
      cacc[nt] = MFMA(a, b, cacc[nt]);
    }
  }

  float* pout = partials + (size_t)bid * 4096;
#pragma unroll
  for (int nt = 0; nt < 4; ++nt)
#pragma unroll
    for (int j = 0; j < 4; ++j)
      pout[(w * 16 + lk * 4 + j) * 64 + nt * 16 + lr] = cacc[nt][j];
}

// ---------------- kernel 3: reduce partials -> ctxT (bf16, /8192, transposed) ----------------
// 64 partial blocks per group now.
__global__ void reduce_ctx_kernel(const float* __restrict__ partials,
                                  unsigned short* __restrict__ ctxTg) {
  const int bid = blockIdx.x, t = threadIdx.x;
  const int gg = bid >> 3, sl = bid & 7;
  const float* base = partials + (size_t)gg * 64 * 4096;
#pragma unroll
  for (int rep = 0; rep < 2; ++rep) {
    const int idx = sl * 512 + rep * 256 + t;  // idx = d*64 + e
    float acc = 0.f;
#pragma unroll 8
    for (int p = 0; p < 64; ++p) acc += base[(size_t)p * 4096 + idx];
    const int d = idx >> 6, e = idx & 63;
    ctxTg[(size_t)gg * 4096 + e * 64 + d] = f2bf(acc * (1.0f / 8192.0f));
  }
}

// ---------------- kernel 4: q projection + LN + out = qn @ ctx ----------------
// Same tiling; acc = 32 regs -> 4 waves/SIMD. LDS 32 KB.
__launch_bounds__(256, 4)
__global__ void q_out_kernel(const unsigned short* __restrict__ xb,
                             const unsigned short* __restrict__ Qt,
                             const unsigned short* __restrict__ ctxTg,
                             const float* __restrict__ lnq_s, const float* __restrict__ lnq_b,
                             float* __restrict__ out) {
  __shared__ __align__(16) char smem[32768];  // phase1: A [64][512]; phase2: A2 16K + ctxT 9.2K

  const int tid = threadIdx.x, lane = tid & 63, w = tid >> 6;
  const int wr = w >> 1, wc = w & 1;
  const int bid = blockIdx.x, rb = bid >> 2, nb = bid & 3;
  const int row0 = rb * 64;
  const int g = row0 >> 10;
  const int lr = lane & 15, lk = lane >> 4;

  stage_a_async(xb + (size_t)row0 * 256, w, lane, smem);

  // T14: issue ctx loads early into regs; LDS-write after the A region is dead.
  const unsigned short* csrc = ctxTg + (size_t)g * 4096 + (tid >> 2) * 64 + (tid & 3) * 16;
  const short8 c0 = *(const short8*)(csrc);
  const short8 c1 = *(const short8*)(csrc + 8);

  const f32x4 z4 = {0.f, 0.f, 0.f, 0.f};
  f32x4 acc[2][4];
#pragma unroll
  for (int i = 0; i < 2; ++i)
#pragma unroll
    for (int j = 0; j < 4; ++j) acc[i][j] = z4;

  const unsigned short* qb = Qt + (size_t)(nb * 128 + wc * 64) * 256;

  __syncthreads();

  // ---- barrier-free GEMM over k=256 ----
#pragma unroll
  for (int ks = 0; ks < 4; ++ks) {
    short8 bq[8];
#pragma unroll
    for (int nt = 0; nt < 4; ++nt) {
      const unsigned short* qr = qb + (size_t)(nt * 16 + lr) * 256 + ks * 64 + lk * 8;
      bq[nt * 2] = *(const short8*)(qr); bq[nt * 2 + 1] = *(const short8*)(qr + 32);
    }
    short8 a0[2], a1[2];
#pragma unroll
    for (int mt = 0; mt < 2; ++mt) {
      const int row = wr * 32 + mt * 16 + lr;
      const int sw = (row & 7) << 4;
      a0[mt] = *(const short8*)(smem + row * 512 + ((ks * 128 + lk * 16) ^ sw));
      a1[mt] = *(const short8*)(smem + row * 512 + ((ks * 128 + 64 + lk * 16) ^ sw));
    }
#pragma unroll
    for (int mt = 0; mt < 2; ++mt)
#pragma unroll
      for (int nt = 0; nt < 4; ++nt) {
        acc[mt][nt] = MFMA(a0[mt], bq[nt * 2],     acc[mt][nt]);
        acc[mt][nt] = MFMA(a1[mt], bq[nt * 2 + 1], acc[mt][nt]);
      }
  }

  chunk_layernorm<2>(acc, lnq_s, lnq_b, lane);

  __syncthreads();   // A reads done; reuse region

  char* A2   = smem;            // [2 ch][64 m][128 B], xor-swizzled
  char* ctxT = smem + 16384;    // [64 e][144 B] padded

  // ctxT LDS write (data already in regs)
  {
    char* dst = ctxT + (tid >> 2) * 144 + (tid & 3) * 32;
    *(short8*)dst        = c0;
    *(short8*)(dst + 16) = c1;
  }
  // qn -> A2
#pragma unroll
  for (int mt = 0; mt < 2; ++mt)
#pragma unroll
    for (int j = 0; j < 4; ++j) {
      const int m = wr * 32 + mt * 16 + lk * 4 + j;
      const int sw = (m & 7) << 4;
#pragma unroll
      for (int nt = 0; nt < 4; ++nt) {
        const int d = nt * 16 + lr;
        *(unsigned short*)(A2 + wc * 8192 + m * 128 + ((d * 2) ^ sw)) = f2bf(acc[mt][nt][j]);
      }
    }
  __syncthreads();

  // out MFMA: out[m][e] = sum_d qn[m][d] * ctx[d][e]; wave: chunk wc, rows wr*32..+32
  f32x4 o[2][4];
#pragma unroll
  for (int i = 0; i < 2; ++i)
#pragma unroll
    for (int j = 0; j < 4; ++j) o[i][j] = z4;

#pragma unroll
  for (int s = 0; s < 2; ++s) {
    short8 a[2], b[4];
#pragma unroll
    for (int mt = 0; mt < 2; ++mt) {
      const int m = wr * 32 + mt * 16 + lr;
      a[mt] = *(const short8*)(A2 + wc * 8192 + m * 128 + ((s * 64 + lk * 16) ^ ((m & 7) << 4)));
    }
#pragma unroll
    for (int nt = 0; nt < 4; ++nt)
      b[nt] = *(const short8*)(ctxT + (nt * 16 + lr) * 144 + s * 64 + lk * 16);
#pragma unroll
    for (int mt = 0; mt < 2; ++mt)
#pragma unroll
      for (int nt = 0; nt < 4; ++nt)
        o[mt][nt] = MFMA(a[mt], b[nt], o[mt][nt]);
  }

  // store: row = row0 + wr*32 + mt*16 + lk*4 + j, col = nb*128 + wc*64 + nt*16 + lr
#pragma unroll
  for (int mt = 0; mt < 2; ++mt)
#pragma unroll
    for (int nt = 0; nt < 4; ++nt)
#pragma unroll
      for (int j = 0; j < 4; ++j) {
        const int n = wr * 32 + mt * 16 + lk * 4 + j;
        out[(size_t)(row0 + n) * FDIM + nb * 128 + wc * 64 + nt * 16 + lr] = o[mt][nt][j];
      }
}

// ---------------- launch ----------------
extern "C" void kernel_launch(void* const* d_in, const int* in_sizes, int n_in,
                              void* d_out, int out_size, void* d_ws, size_t ws_size,
                              hipStream_t stream) {
  (void)in_sizes; (void)n_in; (void)out_size; (void)ws_size;
  const float* x     = (const float*)d_in[0];
  const float* kv    = (const float*)d_in[1];
  const float* Q     = (const float*)d_in[2];
  const float* K     = (const float*)d_in[3];
  const float* V     = (const float*)d_in[4];
  const float* ls    = (const float*)d_in[5];
  const float* lnq_s = (const float*)d_in[6];
  const float* lnq_b = (const float*)d_in[7];
  const float* lnk_s = (const float*)d_in[8];
  const float* lnk_b = (const float*)d_in[9];
  const float* lnv_s = (const float*)d_in[10];
  const float* lnv_b = (const float*)d_in[11];
  float* out = (float*)d_out;

  char* ws = (char*)d_ws;
  unsigned short* Qt   = (unsigned short*)(ws + QT_OFF);
  unsigned short* Kt   = (unsigned short*)(ws + KT_OFF);
  unsigned short* Vt   = (unsigned short*)(ws + VT_OFF);
  unsigned short* ctxT = (unsigned short*)(ws + CTXT_OFF);
  unsigned short* kvb  = (unsigned short*)(ws + KVB_OFF);
  unsigned short* xb   = (unsigned short*)(ws + XB_OFF);
  float* partials      = (float*)(ws + PART_OFF);

  prep_kernel<<<5632, 256, 0, stream>>>(kv, x, Q, K, V, ls, kvb, xb, Qt, Kt, Vt);
  kv_ctx_kernel<<<2048, 256, 0, stream>>>(kvb, Kt, Vt, lnk_s, lnk_b, lnv_s, lnv_b, partials);
  reduce_ctx_kernel<<<256, 256, 0, stream>>>(partials, ctxT);
  q_out_kernel<<<2048, 256, 0, stream>>>(xb, Qt, ctxT, lnq_s, lnq_b, out);
}